// Round 21
// baseline (55.021 us; speedup 1.0000x reference)
//
#include <hip/hip_runtime.h>
#include <hip/hip_bf16.h>

#define EPS 1e-5f
#define NPTS 262144
#define NB 16

typedef __attribute__((ext_vector_type(8))) short bf16x8;
typedef __attribute__((ext_vector_type(4))) float f32x4;

// ws float/u32 offsets
#define WS_E    0        // 192 f
#define WS_T    192      // 1024 f
#define WS_W3   1216     // 2048 u32
#define WS_MAXF 3264     // 2048 u32 final maxima
#define WS_PMOM 5312     // 16*73 f
#define WS_SCRM 6480     // 256*73 f (ends 25168)
#define WS_SMAX 43856    // 256*2048 u32 per-block maxima (2MB)

__device__ inline float decodeu(unsigned u){
  unsigned bits = (u & 0x80000000u) ? (u ^ 0x80000000u) : ~u;
  return __uint_as_float(bits);
}
__device__ inline unsigned f2bf(float f){
  unsigned u = __float_as_uint(f);
  return (u + 0x7FFFu + ((u>>16)&1u)) >> 16;
}
__device__ inline unsigned pack2bf(float lo, float hi){
  return (f2bf(hi)<<16) | (f2bf(lo) & 0xFFFFu);
}
__device__ inline unsigned ordu(float v){
  unsigned bits = __float_as_uint(v);
  return bits ^ (unsigned)(((int)bits>>31) | (int)0x80000000);
}

// ---- kAC: 256 blocks x 512 thr x 2 point-groups; persistent lmax/hist ----
__global__ __launch_bounds__(512) void kAC(const float* __restrict__ feats,
                                           const int* __restrict__ bidx,
                                           const float* __restrict__ W1,
                                           const float* __restrict__ g1,
                                           float* __restrict__ wsf) {
  __shared__ unsigned lmax[NB*128];
  __shared__ __align__(16) float4 sfeat[512];
  __shared__ float hist[4][NB*4];
  __shared__ float red[8*9];
  __shared__ unsigned cnt[NB], base[NB];
  int tid = threadIdx.x;
  int lane = tid&63, wv = tid>>6;
  for (int i=tid;i<NB*128;i+=512) lmax[i]=0u;
  if (tid < 4*NB*4) ((float*)hist)[tid]=0.f;
  // channel weights hoisted (c0 = lane, c1 = lane+64)
  int c0 = lane, c1 = lane+64;
  float sg0 = (g1[c0]>=0.f)?1.f:-1.f;
  float sg1 = (g1[c1]>=0.f)?1.f:-1.f;
  float w00=W1[3*c0]*sg0, w01=W1[3*c0+1]*sg0, w02=W1[3*c0+2]*sg0;
  float w10=W1[3*c1]*sg1, w11=W1[3*c1+1]*sg1, w12=W1[3*c1+2]*sg1;
  int hrep = wv >> 1;
  float a0=0,a1=0,a2=0,a3=0,a4=0,a5=0,a6=0,a7=0,a8=0;
  #pragma unroll 1
  for (int grp=0; grp<2; ++grp){
    if (tid < NB) cnt[tid]=0u;
    __syncthreads();
    int p = (blockIdx.x*2 + grp)*512 + tid;
    float f0=feats[3*p], f1=feats[3*p+1], f2=feats[3*p+2];
    int b = bidx[p];
    atomicAdd(&hist[hrep][b*4+0],f0);
    atomicAdd(&hist[hrep][b*4+1],f1);
    atomicAdd(&hist[hrep][b*4+2],f2);
    atomicAdd(&hist[hrep][b*4+3],1.0f);
    a0+=f0; a1+=f1; a2+=f2;
    a3+=f0*f0; a4+=f0*f1; a5+=f0*f2;
    a6+=f1*f1; a7+=f1*f2; a8+=f2*f2;
    unsigned pos = atomicAdd(&cnt[b], 1u);
    __syncthreads();
    if (tid==0){
      unsigned s=0;
      #pragma unroll
      for (int q=0;q<NB;q++){ base[q]=s; s+=cnt[q]; }
    }
    __syncthreads();
    sfeat[base[b]+pos] = make_float4(f0,f1,f2,__int_as_float(b));
    __syncthreads();
    const float4* sp = &sfeat[wv*64];
    int bcur = -1; float mm0=0.f, mm1=0.f;
    #pragma unroll 8
    for (int k=0;k<64;k++){
      float4 f = sp[k];                    // broadcast ds_read_b128
      float v0 = fmaf(f.z,w02,fmaf(f.y,w01,f.x*w00));
      float v1 = fmaf(f.z,w12,fmaf(f.y,w11,f.x*w10));
      int b2 = __builtin_amdgcn_readfirstlane(__float_as_int(f.w));
      if (b2 != bcur){
        if (bcur >= 0){
          atomicMax(&lmax[bcur*128+c0], ordu(mm0));
          atomicMax(&lmax[bcur*128+c1], ordu(mm1));
        }
        bcur = b2; mm0 = v0; mm1 = v1;
      } else {
        mm0 = fmaxf(mm0,v0); mm1 = fmaxf(mm1,v1);
      }
    }
    atomicMax(&lmax[bcur*128+c0], ordu(mm0));
    atomicMax(&lmax[bcur*128+c1], ordu(mm1));
    __syncthreads();
  }
  { float acc[9]={a0,a1,a2,a3,a4,a5,a6,a7,a8};
    #pragma unroll
    for (int k=0;k<9;k++){
      float v=acc[k];
      v+=__shfl_down(v,32); v+=__shfl_down(v,16); v+=__shfl_down(v,8);
      v+=__shfl_down(v,4);  v+=__shfl_down(v,2);  v+=__shfl_down(v,1);
      if (lane==0) red[wv*9+k]=v;
    }
  }
  __syncthreads();
  float* scrM = wsf + WS_SCRM + blockIdx.x*73;
  if (tid<9){
    float s=0;
    #pragma unroll
    for (int q=0;q<8;q++) s += red[q*9+tid];
    scrM[tid]=s;
  }
  if (tid>=64 && tid<128){
    int i = tid-64;
    scrM[9+i] = hist[0][i]+hist[1][i]+hist[2][i]+hist[3][i];
  }
  unsigned* spo = (unsigned*)wsf + WS_SMAX + (size_t)blockIdx.x*2048;
  for (int i=tid;i<2048;i+=512) spo[i]=lmax[i];
}

// ---- kMx: 128 blocks; maxima 256->FINAL (16 elems/blk); moments 16 partials; W3 pack ----
__global__ __launch_bounds__(512) void kMx(const float* __restrict__ W3,
                                           float* __restrict__ wsf){
  __shared__ unsigned red[32][16];
  __shared__ float mred[2][73];
  int tid = threadIdx.x, blk = blockIdx.x;
  int g = tid >> 4;                        // 32 row-groups of 8 rows
  int e = blk*16 + (tid & 15);
  const unsigned* smax = (const unsigned*)wsf + WS_SMAX;
  unsigned m = 0;
  #pragma unroll 8
  for (int k=g*8; k<g*8+8; k++){
    unsigned t = smax[(size_t)k*2048 + e];
    m = t>m ? t : m;
  }
  red[g][tid&15] = m;
  // moments: blocks 0..15, 16 rows each (8 per half) -> 16 partials
  if (blk < 16 && tid < 146){
    int h = (tid >= 73) ? 1 : 0, mm = tid - 73*h;
    float s = 0; const float* sm0 = wsf + WS_SCRM;
    int k0 = blk*16 + h*8;
    #pragma unroll 4
    for (int k=k0; k<k0+8; k++) s += sm0[k*73 + mm];
    mred[h][mm] = s;
  }
  if (blk >= 32 && blk < 34){
    int q = (blk-32)*512 + tid;
    float4 v = ((const float4*)W3)[q];
    unsigned* w3u = (unsigned*)wsf + WS_W3;
    w3u[2*q]   = pack2bf(v.x, v.y);
    w3u[2*q+1] = pack2bf(v.z, v.w);
  }
  __syncthreads();
  if (tid < 16){
    unsigned u = red[0][tid];
    #pragma unroll
    for (int q=1;q<32;q++){ unsigned t=red[q][tid]; u = t>u?t:u; }
    ((unsigned*)wsf)[WS_MAXF + blk*16 + tid] = u;
  }
  if (blk < 16 && tid < 73)
    wsf[WS_PMOM + blk*73 + tid] = mred[0][tid] + mred[1][tid];
}

// ---- kB2: per-output-channel layer-2 math (16 PMOM partials) ----
__global__ __launch_bounds__(128) void kB2(const float* __restrict__ W1,
    const float* __restrict__ g1, const float* __restrict__ b1,
    const float* __restrict__ W2, const float* __restrict__ g2,
    const float* __restrict__ b2, float* __restrict__ wsf){
  __shared__ float spm[16*73];
  __shared__ float smom[80];
  __shared__ float dred[2][20];
  __shared__ float sfin[20];
  __shared__ float pY[16], pYY[16], hbs[16];
  __shared__ float s2t2[2];
  int tid = threadIdx.x, c = blockIdx.x;
  int lane = tid & 63, wv = tid >> 6;
  for (int i=tid;i<16*73;i+=128) spm[i] = wsf[WS_PMOM + i];
  int j = tid;
  float w2f = W2[c*256 + j];
  float w2b = W2[c*256 + 128 + j];
  float w10 = W1[3*j], w11 = W1[3*j+1], w12 = W1[3*j+2];
  float g1j = g1[j], b1j = b1[j];
  unsigned um[16];
  { const unsigned* mf = (const unsigned*)wsf + WS_MAXF;
    #pragma unroll
    for (int b=0;b<16;b++) um[b] = mf[b*128 + j];
  }
  __syncthreads();
  if (tid < 73){
    float s = 0;
    #pragma unroll
    for (int g=0; g<16; g++) s += spm[g*73 + tid];
    smom[tid] = s;
  }
  __syncthreads();
  const float invN = 1.0f/NPTS;
  float mean = (w10*smom[0]+w11*smom[1]+w12*smom[2])*invN;
  float ex2 = (w10*w10*smom[3]+w11*w11*smom[6]+w12*w12*smom[8]
             + 2.f*(w10*w11*smom[4]+w10*w12*smom[5]+w11*w12*smom[7]))*invN;
  float var = ex2 - mean*mean;
  float sc = g1j*rsqrtf(var+EPS);
  float sh = b1j - mean*sc;
  float asc = fabsf(sc);
  float p[20];
  p[0] = w2f*(sc*w10); p[1] = w2f*(sc*w11); p[2] = w2f*(sc*w12); p[3] = w2f*sh;
  #pragma unroll
  for (int b=0;b<16;b++) p[4+b] = w2b * fmaf(asc, decodeu(um[b]), sh);
  #pragma unroll
  for (int k=0;k<20;k++){
    float v = p[k];
    v+=__shfl_down(v,32); v+=__shfl_down(v,16); v+=__shfl_down(v,8);
    v+=__shfl_down(v,4);  v+=__shfl_down(v,2);  v+=__shfl_down(v,1);
    if (lane==0) dred[wv][k] = v;
  }
  __syncthreads();
  if (tid < 20) sfin[tid] = dred[0][tid] + dred[1][tid];
  __syncthreads();
  if (tid < 16){
    int b = tid;
    float e0=sfin[0],e1=sfin[1],e2=sfin[2],gc=sfin[3];
    float nb = smom[9+b*4+3];
    float hb = gc + sfin[4+b];
    float eS1b = e0*smom[9+b*4]+e1*smom[9+b*4+1]+e2*smom[9+b*4+2];
    hbs[b]=hb; pY[b]=nb*hb; pYY[b]=2.f*hb*eS1b+nb*hb*hb;
  }
  __syncthreads();
  if (tid == 0){
    float e0=sfin[0],e1=sfin[1],e2=sfin[2];
    float sumY = e0*smom[0]+e1*smom[1]+e2*smom[2];
    float sumYY = e0*e0*smom[3]+e1*e1*smom[6]+e2*e2*smom[8]
               + 2.f*(e0*e1*smom[4]+e0*e2*smom[5]+e1*e2*smom[7]);
    #pragma unroll
    for (int b=0;b<16;b++){ sumY += pY[b]; sumYY += pYY[b]; }
    float mean2 = sumY*invN;
    float var2 = sumYY*invN - mean2*mean2;
    float s2 = g2[c]*rsqrtf(var2+EPS);
    float t2 = b2[c] - mean2*s2;
    wsf[WS_E + c]      = e0*s2;
    wsf[WS_E + 64 + c] = e1*s2;
    wsf[WS_E + 128 + c]= e2*s2;
    s2t2[0]=s2; s2t2[1]=t2;
  }
  __syncthreads();
  if (tid < 16) wsf[WS_T + tid*64 + c] = hbs[tid]*s2t2[0] + s2t2[1];
}

// ---- kF: 1024 blocks x 1 tile; no-alias LDS layout; nt stores ----
__global__ __launch_bounds__(256, 4) void kF(const float* __restrict__ feats,
                                             const int* __restrict__ bidx,
                                             const float* __restrict__ wsf,
                                             const float* __restrict__ b3,
                                             float* __restrict__ out) {
  __shared__ __align__(16) unsigned char SB[39936];
  unsigned* zbuf = (unsigned*)SB;            // 32768 B (phase 1/2)
  float* fbuf = (float*)SB;                  // epilogue: 34816 B (union w/ zbuf)
  float* Tl = (float*)(SB + 34816);          // 16*68 f
  float* sEg = (float*)(SB + 39168);         // 192 f
  int tid = threadIdx.x;
  for (int i=tid;i<NB*64;i+=256) Tl[(i>>6)*68 + (i&63)] = wsf[WS_T + i];
  if (tid < 192) sEg[tid] = wsf[WS_E + tid];
  int lane = tid & 63, wv = tid >> 6;
  int col = lane & 15, kgrp = lane >> 4;
  const ushort* w3b = (const ushort*)((const unsigned*)wsf + WS_W3);
  bf16x8 bfr[4][2];
  #pragma unroll
  for (int n=0;n<4;n++)
    #pragma unroll
    for (int kk=0;kk<2;kk++)
      bfr[n][kk] = *(const bf16x8*)(w3b + (n*16+col)*64 + kk*32 + kgrp*8);
  float bias[4];
  #pragma unroll
  for (int n=0;n<4;n++) bias[n] = b3[n*16+col];
  const f32x4* e04 = (const f32x4*)(sEg);
  const f32x4* e14 = (const f32x4*)(sEg + 64);
  const f32x4* e24 = (const f32x4*)(sEg + 128);
  __syncthreads();
  int p0 = (blockIdx.x*4 + wv)*64;
  int p = p0 + lane;
  float f0 = feats[3*p], f1 = feats[3*p+1], f2 = feats[3*p+2];
  int b = bidx[p];
  const f32x4* tb4 = (const f32x4*)&Tl[b*68];
  unsigned rowbase = (unsigned)(wv*64+lane)*32;
  unsigned sw = (lane&7)<<2;
  #pragma unroll
  for (int j=0;j<8;j++){
    unsigned w[4];
    #pragma unroll
    for (int h=0;h<2;h++){
      int cq = j*2 + h;
      f32x4 e0 = e04[cq], e1 = e14[cq], e2 = e24[cq], tp = tb4[cq];
      float y0 = fmaf(e0[0],f0, fmaf(e1[0],f1, fmaf(e2[0],f2, tp[0])));
      float y1 = fmaf(e0[1],f0, fmaf(e1[1],f1, fmaf(e2[1],f2, tp[1])));
      float y2 = fmaf(e0[2],f0, fmaf(e1[2],f1, fmaf(e2[2],f2, tp[2])));
      float y3 = fmaf(e0[3],f0, fmaf(e1[3],f1, fmaf(e2[3],f2, tp[3])));
      w[h*2]   = pack2bf(fmaxf(y0,0.f), fmaxf(y1,0.f));
      w[h*2+1] = pack2bf(fmaxf(y2,0.f), fmaxf(y3,0.f));
    }
    uint4 ch; ch.x=w[0]; ch.y=w[1]; ch.z=w[2]; ch.w=w[3];
    *(uint4*)&zbuf[rowbase + (((unsigned)(j*4)) ^ sw)] = ch;
  }
  __syncthreads();
  bf16x8 af[4][2];
  #pragma unroll
  for (int m=0;m<4;m++){
    int row = m*16 + col;
    unsigned rb = (unsigned)(wv*64+row)*32;
    unsigned sw2 = (unsigned)(row&7)<<2;
    #pragma unroll
    for (int kk=0;kk<2;kk++){
      unsigned off = ((unsigned)(kk*16 + kgrp*4)) ^ sw2;
      af[m][kk] = *(const bf16x8*)&zbuf[rb + off];
    }
  }
  __syncthreads();
  #pragma unroll
  for (int half=0; half<2; half++){
    f32x4 acc[2][4];
    #pragma unroll
    for (int mi=0;mi<2;mi++)
      #pragma unroll
      for (int n=0;n<4;n++)
        acc[mi][n] = (f32x4){0.f,0.f,0.f,0.f};
    #pragma unroll
    for (int kk=0;kk<2;kk++)
      #pragma unroll
      for (int mi=0;mi<2;mi++)
        #pragma unroll
        for (int n=0;n<4;n++)
          acc[mi][n] = __builtin_amdgcn_mfma_f32_16x16x32_bf16(af[half*2+mi][kk], bfr[n][kk], acc[mi][n], 0,0,0);
    #pragma unroll
    for (int mi=0;mi<2;mi++){
      #pragma unroll
      for (int n=0;n<4;n++){
        #pragma unroll
        for (int r=0;r<4;r++)
          fbuf[wv*2176 + (mi*16 + kgrp*4 + r)*68 + n*16 + col] = acc[mi][n][r] + bias[n];
      }
    }
    __syncthreads();
    #pragma unroll
    for (int it=0; it<8; it++){
      int idx = it*256 + tid;
      int gr = idx >> 4;
      int c4 = (idx & 15) * 4;
      f32x4 v = *(const f32x4*)&fbuf[(gr>>5)*2176 + (gr&31)*68 + c4];
      int orow = blockIdx.x*256 + (gr>>5)*64 + half*32 + (gr&31);
      __builtin_nontemporal_store(v, (f32x4*)&out[(size_t)orow*64 + c4]);
    }
    __syncthreads();
  }
}

extern "C" void kernel_launch(void* const* d_in, const int* in_sizes, int n_in,
                              void* d_out, int out_size, void* d_ws, size_t ws_size,
                              hipStream_t stream) {
  const float* feats = (const float*)d_in[0];
  const int*   bidx  = (const int*)d_in[1];
  const float* W1 = (const float*)d_in[2];
  const float* g1 = (const float*)d_in[3];
  const float* b1 = (const float*)d_in[4];
  const float* W2 = (const float*)d_in[5];
  const float* g2 = (const float*)d_in[6];
  const float* b2 = (const float*)d_in[7];
  const float* W3 = (const float*)d_in[8];
  const float* b3 = (const float*)d_in[9];
  float* wsf = (float*)d_ws;
  float* out = (float*)d_out;
  kAC<<<256, 512, 0, stream>>>(feats, bidx, W1, g1, wsf);
  kMx<<<128, 512, 0, stream>>>(W3, wsf);
  kB2<<<64, 128, 0, stream>>>(W1, g1, b1, W2, g2, b2, wsf);
  kF<<<1024, 256, 0, stream>>>(feats, bidx, wsf, b3, out);
}

// Round 22
// 53.620 us; speedup vs baseline: 1.0261x; 1.0261x over previous
//
#include <hip/hip_runtime.h>
#include <hip/hip_bf16.h>

#define EPS 1e-5f
#define NPTS 262144
#define NB 16

typedef __attribute__((ext_vector_type(8))) short bf16x8;
typedef __attribute__((ext_vector_type(4))) float f32x4;

// ws float/u32 offsets
#define WS_E    0        // 192 f
#define WS_T    192      // 1024 f
#define WS_W3   1216     // 2048 u32
#define WS_MAXF 3264     // 2048 u32 final maxima
#define WS_PMOM 5312     // 16*73 f
#define WS_SCRM 6480     // 512*73 f (ends 43856)
#define WS_SMAX 43856    // 512*2048 u32 per-block maxima (4MB)

__device__ inline float decodeu(unsigned u){
  unsigned bits = (u & 0x80000000u) ? (u ^ 0x80000000u) : ~u;
  return __uint_as_float(bits);
}
__device__ inline unsigned f2bf(float f){
  unsigned u = __float_as_uint(f);
  return (u + 0x7FFFu + ((u>>16)&1u)) >> 16;
}
__device__ inline unsigned pack2bf(float lo, float hi){
  return (f2bf(hi)<<16) | (f2bf(lo) & 0xFFFFu);
}
__device__ inline unsigned ordu(float v){
  unsigned bits = __float_as_uint(v);
  return bits ^ (unsigned)(((int)bits>>31) | (int)0x80000000);
}

// ---- kAC: 512 blocks x 512 thr; bucket-sorted run-max (R20 proven) ----
__global__ __launch_bounds__(512) void kAC(const float* __restrict__ feats,
                                           const int* __restrict__ bidx,
                                           const float* __restrict__ W1,
                                           const float* __restrict__ g1,
                                           float* __restrict__ wsf) {
  __shared__ unsigned lmax[NB*128];
  __shared__ __align__(16) float4 sfeat[512];
  __shared__ float hist[4][NB*4];
  __shared__ float red[8*9];
  __shared__ unsigned cnt[NB], base[NB];
  int tid = threadIdx.x;
  int lane = tid&63, wv = tid>>6;
  for (int i=tid;i<NB*128;i+=512) lmax[i]=0u;
  if (tid < 4*NB*4) ((float*)hist)[tid]=0.f;
  if (tid < NB) cnt[tid]=0u;
  __syncthreads();
  int p = blockIdx.x*512 + tid;
  float f0=feats[3*p], f1=feats[3*p+1], f2=feats[3*p+2];
  int b = bidx[p];
  int hrep = wv >> 1;
  atomicAdd(&hist[hrep][b*4+0],f0);
  atomicAdd(&hist[hrep][b*4+1],f1);
  atomicAdd(&hist[hrep][b*4+2],f2);
  atomicAdd(&hist[hrep][b*4+3],1.0f);
  unsigned pos = atomicAdd(&cnt[b], 1u);
  { float acc[9]={f0,f1,f2,f0*f0,f0*f1,f0*f2,f1*f1,f1*f2,f2*f2};
    #pragma unroll
    for (int k=0;k<9;k++){
      float v=acc[k];
      v+=__shfl_down(v,32); v+=__shfl_down(v,16); v+=__shfl_down(v,8);
      v+=__shfl_down(v,4);  v+=__shfl_down(v,2);  v+=__shfl_down(v,1);
      if (lane==0) red[wv*9+k]=v;
    }
  }
  __syncthreads();
  if (tid==0){
    unsigned s=0;
    #pragma unroll
    for (int q=0;q<NB;q++){ base[q]=s; s+=cnt[q]; }
  }
  __syncthreads();
  sfeat[base[b]+pos] = make_float4(f0,f1,f2,__int_as_float(b));
  __syncthreads();
  int c0 = lane, c1 = lane+64;
  float sg0 = (g1[c0]>=0.f)?1.f:-1.f;
  float sg1 = (g1[c1]>=0.f)?1.f:-1.f;
  float w00=W1[3*c0]*sg0, w01=W1[3*c0+1]*sg0, w02=W1[3*c0+2]*sg0;
  float w10=W1[3*c1]*sg1, w11=W1[3*c1+1]*sg1, w12=W1[3*c1+2]*sg1;
  const float4* sp = &sfeat[wv*64];
  int bcur = -1; float mm0=0.f, mm1=0.f;
  #pragma unroll 8
  for (int k=0;k<64;k++){
    float4 f = sp[k];
    float v0 = fmaf(f.z,w02,fmaf(f.y,w01,f.x*w00));
    float v1 = fmaf(f.z,w12,fmaf(f.y,w11,f.x*w10));
    int b2 = __builtin_amdgcn_readfirstlane(__float_as_int(f.w));
    if (b2 != bcur){
      if (bcur >= 0){
        atomicMax(&lmax[bcur*128+c0], ordu(mm0));
        atomicMax(&lmax[bcur*128+c1], ordu(mm1));
      }
      bcur = b2; mm0 = v0; mm1 = v1;
    } else {
      mm0 = fmaxf(mm0,v0); mm1 = fmaxf(mm1,v1);
    }
  }
  atomicMax(&lmax[bcur*128+c0], ordu(mm0));
  atomicMax(&lmax[bcur*128+c1], ordu(mm1));
  __syncthreads();
  float* scrM = wsf + WS_SCRM + blockIdx.x*73;
  if (tid<9){
    float s=0;
    #pragma unroll
    for (int q=0;q<8;q++) s += red[q*9+tid];
    scrM[tid]=s;
  }
  if (tid>=64 && tid<128){
    int i = tid-64;
    scrM[9+i] = hist[0][i]+hist[1][i]+hist[2][i]+hist[3][i];
  }
  unsigned* spo = (unsigned*)wsf + WS_SMAX + (size_t)blockIdx.x*2048;
  for (int i=tid;i<2048;i+=512) spo[i]=lmax[i];
}

// ---- kMx: 128 blocks; maxima 512->FINAL; moments 16 partials; W3 pack (R20) ----
__global__ __launch_bounds__(512) void kMx(const float* __restrict__ W3,
                                           float* __restrict__ wsf){
  __shared__ unsigned red[32][16];
  __shared__ float mred[2][73];
  int tid = threadIdx.x, blk = blockIdx.x;
  int g = tid >> 4;
  int e = blk*16 + (tid & 15);
  const unsigned* smax = (const unsigned*)wsf + WS_SMAX;
  unsigned m = 0;
  #pragma unroll 8
  for (int k=g*16; k<g*16+16; k++){
    unsigned t = smax[(size_t)k*2048 + e];
    m = t>m ? t : m;
  }
  red[g][tid&15] = m;
  if (blk < 16 && tid < 146){
    int h = (tid >= 73) ? 1 : 0, mm = tid - 73*h;
    float s = 0; const float* sm0 = wsf + WS_SCRM;
    int k0 = blk*32 + h*16;
    #pragma unroll 4
    for (int k=k0; k<k0+16; k++) s += sm0[k*73 + mm];
    mred[h][mm] = s;
  }
  if (blk >= 32 && blk < 34){
    int q = (blk-32)*512 + tid;
    float4 v = ((const float4*)W3)[q];
    unsigned* w3u = (unsigned*)wsf + WS_W3;
    w3u[2*q]   = pack2bf(v.x, v.y);
    w3u[2*q+1] = pack2bf(v.z, v.w);
  }
  __syncthreads();
  if (tid < 16){
    unsigned u = red[0][tid];
    #pragma unroll
    for (int q=1;q<32;q++){ unsigned t=red[q][tid]; u = t>u?t:u; }
    ((unsigned*)wsf)[WS_MAXF + blk*16 + tid] = u;
  }
  if (blk < 16 && tid < 73)
    wsf[WS_PMOM + blk*73 + tid] = mred[0][tid] + mred[1][tid];
}

// ---- kB2: per-output-channel layer-2 math (R20) ----
__global__ __launch_bounds__(128) void kB2(const float* __restrict__ W1,
    const float* __restrict__ g1, const float* __restrict__ b1,
    const float* __restrict__ W2, const float* __restrict__ g2,
    const float* __restrict__ b2, float* __restrict__ wsf){
  __shared__ float spm[16*73];
  __shared__ float smom[80];
  __shared__ float dred[2][20];
  __shared__ float sfin[20];
  __shared__ float pY[16], pYY[16], hbs[16];
  __shared__ float s2t2[2];
  int tid = threadIdx.x, c = blockIdx.x;
  int lane = tid & 63, wv = tid >> 6;
  for (int i=tid;i<16*73;i+=128) spm[i] = wsf[WS_PMOM + i];
  int j = tid;
  float w2f = W2[c*256 + j];
  float w2b = W2[c*256 + 128 + j];
  float w10 = W1[3*j], w11 = W1[3*j+1], w12 = W1[3*j+2];
  float g1j = g1[j], b1j = b1[j];
  unsigned um[16];
  { const unsigned* mf = (const unsigned*)wsf + WS_MAXF;
    #pragma unroll
    for (int b=0;b<16;b++) um[b] = mf[b*128 + j];
  }
  __syncthreads();
  if (tid < 73){
    float s = 0;
    #pragma unroll
    for (int g=0; g<16; g++) s += spm[g*73 + tid];
    smom[tid] = s;
  }
  __syncthreads();
  const float invN = 1.0f/NPTS;
  float mean = (w10*smom[0]+w11*smom[1]+w12*smom[2])*invN;
  float ex2 = (w10*w10*smom[3]+w11*w11*smom[6]+w12*w12*smom[8]
             + 2.f*(w10*w11*smom[4]+w10*w12*smom[5]+w11*w12*smom[7]))*invN;
  float var = ex2 - mean*mean;
  float sc = g1j*rsqrtf(var+EPS);
  float sh = b1j - mean*sc;
  float asc = fabsf(sc);
  float p[20];
  p[0] = w2f*(sc*w10); p[1] = w2f*(sc*w11); p[2] = w2f*(sc*w12); p[3] = w2f*sh;
  #pragma unroll
  for (int b=0;b<16;b++) p[4+b] = w2b * fmaf(asc, decodeu(um[b]), sh);
  #pragma unroll
  for (int k=0;k<20;k++){
    float v = p[k];
    v+=__shfl_down(v,32); v+=__shfl_down(v,16); v+=__shfl_down(v,8);
    v+=__shfl_down(v,4);  v+=__shfl_down(v,2);  v+=__shfl_down(v,1);
    if (lane==0) dred[wv][k] = v;
  }
  __syncthreads();
  if (tid < 20) sfin[tid] = dred[0][tid] + dred[1][tid];
  __syncthreads();
  if (tid < 16){
    int b = tid;
    float e0=sfin[0],e1=sfin[1],e2=sfin[2],gc=sfin[3];
    float nb = smom[9+b*4+3];
    float hb = gc + sfin[4+b];
    float eS1b = e0*smom[9+b*4]+e1*smom[9+b*4+1]+e2*smom[9+b*4+2];
    hbs[b]=hb; pY[b]=nb*hb; pYY[b]=2.f*hb*eS1b+nb*hb*hb;
  }
  __syncthreads();
  if (tid == 0){
    float e0=sfin[0],e1=sfin[1],e2=sfin[2];
    float sumY = e0*smom[0]+e1*smom[1]+e2*smom[2];
    float sumYY = e0*e0*smom[3]+e1*e1*smom[6]+e2*e2*smom[8]
               + 2.f*(e0*e1*smom[4]+e0*e2*smom[5]+e1*e2*smom[7]);
    #pragma unroll
    for (int b=0;b<16;b++){ sumY += pY[b]; sumYY += pYY[b]; }
    float mean2 = sumY*invN;
    float var2 = sumYY*invN - mean2*mean2;
    float s2 = g2[c]*rsqrtf(var2+EPS);
    float t2 = b2[c] - mean2*s2;
    wsf[WS_E + c]      = e0*s2;
    wsf[WS_E + 64 + c] = e1*s2;
    wsf[WS_E + 128 + c]= e2*s2;
    s2t2[0]=s2; s2t2[1]=t2;
  }
  __syncthreads();
  if (tid < 16) wsf[WS_T + tid*64 + c] = hbs[tid]*s2t2[0] + s2t2[1];
}

// ---- kF: BARRIER-FREE after staging; all LDS deps wave-local ----
__global__ __launch_bounds__(256, 4) void kF(const float* __restrict__ feats,
                                             const int* __restrict__ bidx,
                                             const float* __restrict__ wsf,
                                             const float* __restrict__ b3,
                                             float* __restrict__ out) {
  __shared__ __align__(16) unsigned char SB[37888];
  unsigned* zbuf = (unsigned*)SB;            // 4 waves x 64 rows x 128B (wave-local slices)
  float* Tl = (float*)(SB + 32768);          // 16*68 f
  float* sEg = (float*)(SB + 37120);         // 192 f
  int tid = threadIdx.x;
  for (int i=tid;i<NB*64;i+=256) Tl[(i>>6)*68 + (i&63)] = wsf[WS_T + i];
  if (tid < 192) sEg[tid] = wsf[WS_E + tid];
  int lane = tid & 63, wv = tid >> 6;
  int col = lane & 15, kgrp = lane >> 4;
  const ushort* w3b = (const ushort*)((const unsigned*)wsf + WS_W3);
  bf16x8 bfr[4][2];
  #pragma unroll
  for (int n=0;n<4;n++)
    #pragma unroll
    for (int kk=0;kk<2;kk++)
      bfr[n][kk] = *(const bf16x8*)(w3b + (n*16+col)*64 + kk*32 + kgrp*8);
  float bias[4];
  #pragma unroll
  for (int n=0;n<4;n++) bias[n] = b3[n*16+col];
  const f32x4* e04 = (const f32x4*)(sEg);
  const f32x4* e14 = (const f32x4*)(sEg + 64);
  const f32x4* e24 = (const f32x4*)(sEg + 128);
  __syncthreads();                            // ONLY block barrier (staging)
  int p0 = (blockIdx.x*4 + wv)*64;
  int p = p0 + lane;
  float f0 = feats[3*p], f1 = feats[3*p+1], f2 = feats[3*p+2];
  int b = bidx[p];
  const f32x4* tb4 = (const f32x4*)&Tl[b*68];
  unsigned rowbase = (unsigned)(wv*64+lane)*32;
  unsigned sw = (lane&7)<<2;
  #pragma unroll
  for (int j=0;j<8;j++){
    unsigned w[4];
    #pragma unroll
    for (int h=0;h<2;h++){
      int cq = j*2 + h;
      f32x4 e0 = e04[cq], e1 = e14[cq], e2 = e24[cq], tp = tb4[cq];
      float y0 = fmaf(e0[0],f0, fmaf(e1[0],f1, fmaf(e2[0],f2, tp[0])));
      float y1 = fmaf(e0[1],f0, fmaf(e1[1],f1, fmaf(e2[1],f2, tp[1])));
      float y2 = fmaf(e0[2],f0, fmaf(e1[2],f1, fmaf(e2[2],f2, tp[2])));
      float y3 = fmaf(e0[3],f0, fmaf(e1[3],f1, fmaf(e2[3],f2, tp[3])));
      w[h*2]   = pack2bf(fmaxf(y0,0.f), fmaxf(y1,0.f));
      w[h*2+1] = pack2bf(fmaxf(y2,0.f), fmaxf(y3,0.f));
    }
    uint4 ch; ch.x=w[0]; ch.y=w[1]; ch.z=w[2]; ch.w=w[3];
    *(uint4*)&zbuf[rowbase + (((unsigned)(j*4)) ^ sw)] = ch;
  }
  // wave-local: my wave's 64 zbuf rows written only by my wave
  asm volatile("s_waitcnt lgkmcnt(0)" ::: "memory");
  __builtin_amdgcn_sched_barrier(0);
  bf16x8 af[4][2];
  #pragma unroll
  for (int m=0;m<4;m++){
    int row = m*16 + col;
    unsigned rb = (unsigned)(wv*64+row)*32;
    unsigned sw2 = (unsigned)(row&7)<<2;
    #pragma unroll
    for (int kk=0;kk<2;kk++){
      unsigned off = ((unsigned)(kk*16 + kgrp*4)) ^ sw2;
      af[m][kk] = *(const bf16x8*)&zbuf[rb + off];
    }
  }
  asm volatile("s_waitcnt lgkmcnt(0)" ::: "memory");  // af loaded before fwave overwrite
  __builtin_amdgcn_sched_barrier(0);
  float* fwave = (float*)(SB + wv*8192);      // reuse my wave's zbuf slice: [32][64] f32
  #pragma unroll
  for (int half=0; half<2; half++){
    f32x4 acc[2][4];
    #pragma unroll
    for (int mi=0;mi<2;mi++)
      #pragma unroll
      for (int n=0;n<4;n++)
        acc[mi][n] = (f32x4){0.f,0.f,0.f,0.f};
    #pragma unroll
    for (int kk=0;kk<2;kk++)
      #pragma unroll
      for (int mi=0;mi<2;mi++)
        #pragma unroll
        for (int n=0;n<4;n++)
          acc[mi][n] = __builtin_amdgcn_mfma_f32_16x16x32_bf16(af[half*2+mi][kk], bfr[n][kk], acc[mi][n], 0,0,0);
    #pragma unroll
    for (int mi=0;mi<2;mi++){
      #pragma unroll
      for (int n=0;n<4;n++){
        #pragma unroll
        for (int r=0;r<4;r++)
          fwave[(mi*16 + kgrp*4 + r)*64 + n*16 + col] = acc[mi][n][r] + bias[n];
      }
    }
    asm volatile("s_waitcnt lgkmcnt(0)" ::: "memory");
    __builtin_amdgcn_sched_barrier(0);
    #pragma unroll
    for (int it=0; it<8; it++){
      int idx = it*64 + lane;
      int r = idx >> 4;
      int c4 = (idx & 15) * 4;
      f32x4 v = *(const f32x4*)&fwave[r*64 + c4];
      int orow = p0 + half*32 + r;
      __builtin_nontemporal_store(v, (f32x4*)&out[(size_t)orow*64 + c4]);
    }
    asm volatile("s_waitcnt lgkmcnt(0)" ::: "memory");  // reads done before next half's writes
    __builtin_amdgcn_sched_barrier(0);
  }
}

extern "C" void kernel_launch(void* const* d_in, const int* in_sizes, int n_in,
                              void* d_out, int out_size, void* d_ws, size_t ws_size,
                              hipStream_t stream) {
  const float* feats = (const float*)d_in[0];
  const int*   bidx  = (const int*)d_in[1];
  const float* W1 = (const float*)d_in[2];
  const float* g1 = (const float*)d_in[3];
  const float* b1 = (const float*)d_in[4];
  const float* W2 = (const float*)d_in[5];
  const float* g2 = (const float*)d_in[6];
  const float* b2 = (const float*)d_in[7];
  const float* W3 = (const float*)d_in[8];
  const float* b3 = (const float*)d_in[9];
  float* wsf = (float*)d_ws;
  float* out = (float*)d_out;
  kAC<<<512, 512, 0, stream>>>(feats, bidx, W1, g1, wsf);
  kMx<<<128, 512, 0, stream>>>(W3, wsf);
  kB2<<<64, 128, 0, stream>>>(W1, g1, b1, W2, g2, b2, wsf);
  kF<<<1024, 256, 0, stream>>>(feats, bidx, wsf, b3, out);
}

// Round 23
// 52.639 us; speedup vs baseline: 1.0453x; 1.0186x over previous
//
#include <hip/hip_runtime.h>
#include <hip/hip_bf16.h>

#define EPS 1e-5f
#define NPTS 262144
#define NB 16

typedef __attribute__((ext_vector_type(8))) short bf16x8;
typedef __attribute__((ext_vector_type(4))) float f32x4;

// ws float/u32 offsets
#define WS_E    0        // 192 f
#define WS_T    192      // 1024 f
#define WS_W3   1216     // 2048 u32
#define WS_MAXF 3264     // 2048 u32 final maxima
#define WS_PMOM 5312     // 16*73 f
#define WS_SCRM 6480     // 512*73 f (ends 43856)
#define WS_SMAX 43856    // 512*2048 u32 per-block maxima (4MB)

__device__ inline float decodeu(unsigned u){
  unsigned bits = (u & 0x80000000u) ? (u ^ 0x80000000u) : ~u;
  return __uint_as_float(bits);
}
__device__ inline unsigned f2bf(float f){
  unsigned u = __float_as_uint(f);
  return (u + 0x7FFFu + ((u>>16)&1u)) >> 16;
}
__device__ inline unsigned pack2bf(float lo, float hi){
  return (f2bf(hi)<<16) | (f2bf(lo) & 0xFFFFu);
}
__device__ inline unsigned ordu(float v){
  unsigned bits = __float_as_uint(v);
  return bits ^ (unsigned)(((int)bits>>31) | (int)0x80000000);
}

// ---- kAC: 512 blocks x 1024 thr (32 waves/CU); max phase = 16 waves x 32 pts ----
__global__ __launch_bounds__(1024) void kAC(const float* __restrict__ feats,
                                            const int* __restrict__ bidx,
                                            const float* __restrict__ W1,
                                            const float* __restrict__ g1,
                                            float* __restrict__ wsf) {
  __shared__ unsigned lmax[NB*128];
  __shared__ __align__(16) float4 sfeat[512];
  __shared__ float hist[4][NB*4];
  __shared__ float red[8*9];
  __shared__ unsigned cnt[NB], base[NB];
  int tid = threadIdx.x;
  int lane = tid&63, wv = tid>>6;           // 16 waves
  for (int i=tid;i<NB*128;i+=1024) lmax[i]=0u;
  if (tid < 4*NB*4) ((float*)hist)[tid]=0.f;
  if (tid < NB) cnt[tid]=0u;
  __syncthreads();
  // staging half: threads 0..511 own one point each
  bool stager = (tid < 512);
  float f0=0.f, f1=0.f, f2=0.f; int b=0; unsigned pos=0;
  if (stager){
    int p = blockIdx.x*512 + tid;
    f0=feats[3*p]; f1=feats[3*p+1]; f2=feats[3*p+2];
    b = bidx[p];
    int hrep = wv >> 1;                     // waves 0..7 -> 4 replicas
    atomicAdd(&hist[hrep][b*4+0],f0);
    atomicAdd(&hist[hrep][b*4+1],f1);
    atomicAdd(&hist[hrep][b*4+2],f2);
    atomicAdd(&hist[hrep][b*4+3],1.0f);
    pos = atomicAdd(&cnt[b], 1u);
  }
  if (wv < 8){                               // moments from staging waves
    float acc[9]={f0,f1,f2,f0*f0,f0*f1,f0*f2,f1*f1,f1*f2,f2*f2};
    #pragma unroll
    for (int k=0;k<9;k++){
      float v=acc[k];
      v+=__shfl_down(v,32); v+=__shfl_down(v,16); v+=__shfl_down(v,8);
      v+=__shfl_down(v,4);  v+=__shfl_down(v,2);  v+=__shfl_down(v,1);
      if (lane==0) red[wv*9+k]=v;
    }
  }
  __syncthreads();
  if (tid==0){
    unsigned s=0;
    #pragma unroll
    for (int q=0;q<NB;q++){ base[q]=s; s+=cnt[q]; }
  }
  __syncthreads();
  if (stager) sfeat[base[b]+pos] = make_float4(f0,f1,f2,__int_as_float(b));
  __syncthreads();
  // max phase: 16 waves x 32 sorted points each; channels c0/c1 per lane
  int c0 = lane, c1 = lane+64;
  float sg0 = (g1[c0]>=0.f)?1.f:-1.f;
  float sg1 = (g1[c1]>=0.f)?1.f:-1.f;
  float w00=W1[3*c0]*sg0, w01=W1[3*c0+1]*sg0, w02=W1[3*c0+2]*sg0;
  float w10=W1[3*c1]*sg1, w11=W1[3*c1+1]*sg1, w12=W1[3*c1+2]*sg1;
  const float4* sp = &sfeat[wv*32];
  int bcur = -1; float mm0=0.f, mm1=0.f;
  #pragma unroll 8
  for (int k=0;k<32;k++){
    float4 f = sp[k];                       // broadcast ds_read_b128
    float v0 = fmaf(f.z,w02,fmaf(f.y,w01,f.x*w00));
    float v1 = fmaf(f.z,w12,fmaf(f.y,w11,f.x*w10));
    int b2 = __builtin_amdgcn_readfirstlane(__float_as_int(f.w));
    if (b2 != bcur){
      if (bcur >= 0){
        atomicMax(&lmax[bcur*128+c0], ordu(mm0));
        atomicMax(&lmax[bcur*128+c1], ordu(mm1));
      }
      bcur = b2; mm0 = v0; mm1 = v1;
    } else {
      mm0 = fmaxf(mm0,v0); mm1 = fmaxf(mm1,v1);
    }
  }
  atomicMax(&lmax[bcur*128+c0], ordu(mm0));
  atomicMax(&lmax[bcur*128+c1], ordu(mm1));
  __syncthreads();
  float* scrM = wsf + WS_SCRM + blockIdx.x*73;
  if (tid<9){
    float s=0;
    #pragma unroll
    for (int q=0;q<8;q++) s += red[q*9+tid];
    scrM[tid]=s;
  }
  if (tid>=64 && tid<128){
    int i = tid-64;
    scrM[9+i] = hist[0][i]+hist[1][i]+hist[2][i]+hist[3][i];
  }
  unsigned* spo = (unsigned*)wsf + WS_SMAX + (size_t)blockIdx.x*2048;
  for (int i=tid;i<2048;i+=1024) spo[i]=lmax[i];
}

// ---- kMx: 128 blocks; maxima 512->FINAL; moments 16 partials; W3 pack ----
__global__ __launch_bounds__(512) void kMx(const float* __restrict__ W3,
                                           float* __restrict__ wsf){
  __shared__ unsigned red[32][16];
  __shared__ float mred[2][73];
  int tid = threadIdx.x, blk = blockIdx.x;
  int g = tid >> 4;
  int e = blk*16 + (tid & 15);
  const unsigned* smax = (const unsigned*)wsf + WS_SMAX;
  unsigned m = 0;
  #pragma unroll 8
  for (int k=g*16; k<g*16+16; k++){
    unsigned t = smax[(size_t)k*2048 + e];
    m = t>m ? t : m;
  }
  red[g][tid&15] = m;
  if (blk < 16 && tid < 146){
    int h = (tid >= 73) ? 1 : 0, mm = tid - 73*h;
    float s = 0; const float* sm0 = wsf + WS_SCRM;
    int k0 = blk*32 + h*16;
    #pragma unroll 4
    for (int k=k0; k<k0+16; k++) s += sm0[k*73 + mm];
    mred[h][mm] = s;
  }
  if (blk >= 32 && blk < 34){
    int q = (blk-32)*512 + tid;
    float4 v = ((const float4*)W3)[q];
    unsigned* w3u = (unsigned*)wsf + WS_W3;
    w3u[2*q]   = pack2bf(v.x, v.y);
    w3u[2*q+1] = pack2bf(v.z, v.w);
  }
  __syncthreads();
  if (tid < 16){
    unsigned u = red[0][tid];
    #pragma unroll
    for (int q=1;q<32;q++){ unsigned t=red[q][tid]; u = t>u?t:u; }
    ((unsigned*)wsf)[WS_MAXF + blk*16 + tid] = u;
  }
  if (blk < 16 && tid < 73)
    wsf[WS_PMOM + blk*73 + tid] = mred[0][tid] + mred[1][tid];
}

// ---- kB2: per-output-channel layer-2 math ----
__global__ __launch_bounds__(128) void kB2(const float* __restrict__ W1,
    const float* __restrict__ g1, const float* __restrict__ b1,
    const float* __restrict__ W2, const float* __restrict__ g2,
    const float* __restrict__ b2, float* __restrict__ wsf){
  __shared__ float spm[16*73];
  __shared__ float smom[80];
  __shared__ float dred[2][20];
  __shared__ float sfin[20];
  __shared__ float pY[16], pYY[16], hbs[16];
  __shared__ float s2t2[2];
  int tid = threadIdx.x, c = blockIdx.x;
  int lane = tid & 63, wv = tid >> 6;
  for (int i=tid;i<16*73;i+=128) spm[i] = wsf[WS_PMOM + i];
  int j = tid;
  float w2f = W2[c*256 + j];
  float w2b = W2[c*256 + 128 + j];
  float w10 = W1[3*j], w11 = W1[3*j+1], w12 = W1[3*j+2];
  float g1j = g1[j], b1j = b1[j];
  unsigned um[16];
  { const unsigned* mf = (const unsigned*)wsf + WS_MAXF;
    #pragma unroll
    for (int b=0;b<16;b++) um[b] = mf[b*128 + j];
  }
  __syncthreads();
  if (tid < 73){
    float s = 0;
    #pragma unroll
    for (int g=0; g<16; g++) s += spm[g*73 + tid];
    smom[tid] = s;
  }
  __syncthreads();
  const float invN = 1.0f/NPTS;
  float mean = (w10*smom[0]+w11*smom[1]+w12*smom[2])*invN;
  float ex2 = (w10*w10*smom[3]+w11*w11*smom[6]+w12*w12*smom[8]
             + 2.f*(w10*w11*smom[4]+w10*w12*smom[5]+w11*w12*smom[7]))*invN;
  float var = ex2 - mean*mean;
  float sc = g1j*rsqrtf(var+EPS);
  float sh = b1j - mean*sc;
  float asc = fabsf(sc);
  float p[20];
  p[0] = w2f*(sc*w10); p[1] = w2f*(sc*w11); p[2] = w2f*(sc*w12); p[3] = w2f*sh;
  #pragma unroll
  for (int b=0;b<16;b++) p[4+b] = w2b * fmaf(asc, decodeu(um[b]), sh);
  #pragma unroll
  for (int k=0;k<20;k++){
    float v = p[k];
    v+=__shfl_down(v,32); v+=__shfl_down(v,16); v+=__shfl_down(v,8);
    v+=__shfl_down(v,4);  v+=__shfl_down(v,2);  v+=__shfl_down(v,1);
    if (lane==0) dred[wv][k] = v;
  }
  __syncthreads();
  if (tid < 20) sfin[tid] = dred[0][tid] + dred[1][tid];
  __syncthreads();
  if (tid < 16){
    int b = tid;
    float e0=sfin[0],e1=sfin[1],e2=sfin[2],gc=sfin[3];
    float nb = smom[9+b*4+3];
    float hb = gc + sfin[4+b];
    float eS1b = e0*smom[9+b*4]+e1*smom[9+b*4+1]+e2*smom[9+b*4+2];
    hbs[b]=hb; pY[b]=nb*hb; pYY[b]=2.f*hb*eS1b+nb*hb*hb;
  }
  __syncthreads();
  if (tid == 0){
    float e0=sfin[0],e1=sfin[1],e2=sfin[2];
    float sumY = e0*smom[0]+e1*smom[1]+e2*smom[2];
    float sumYY = e0*e0*smom[3]+e1*e1*smom[6]+e2*e2*smom[8]
               + 2.f*(e0*e1*smom[4]+e0*e2*smom[5]+e1*e2*smom[7]);
    #pragma unroll
    for (int b=0;b<16;b++){ sumY += pY[b]; sumYY += pYY[b]; }
    float mean2 = sumY*invN;
    float var2 = sumYY*invN - mean2*mean2;
    float s2 = g2[c]*rsqrtf(var2+EPS);
    float t2 = b2[c] - mean2*s2;
    wsf[WS_E + c]      = e0*s2;
    wsf[WS_E + 64 + c] = e1*s2;
    wsf[WS_E + 128 + c]= e2*s2;
    s2t2[0]=s2; s2t2[1]=t2;
  }
  __syncthreads();
  if (tid < 16) wsf[WS_T + tid*64 + c] = hbs[tid]*s2t2[0] + s2t2[1];
}

// ---- kF: barrier-free after staging; wave-local LDS (R22 best) ----
__global__ __launch_bounds__(256, 4) void kF(const float* __restrict__ feats,
                                             const int* __restrict__ bidx,
                                             const float* __restrict__ wsf,
                                             const float* __restrict__ b3,
                                             float* __restrict__ out) {
  __shared__ __align__(16) unsigned char SB[37888];
  unsigned* zbuf = (unsigned*)SB;
  float* Tl = (float*)(SB + 32768);
  float* sEg = (float*)(SB + 37120);
  int tid = threadIdx.x;
  for (int i=tid;i<NB*64;i+=256) Tl[(i>>6)*68 + (i&63)] = wsf[WS_T + i];
  if (tid < 192) sEg[tid] = wsf[WS_E + tid];
  int lane = tid & 63, wv = tid >> 6;
  int col = lane & 15, kgrp = lane >> 4;
  const ushort* w3b = (const ushort*)((const unsigned*)wsf + WS_W3);
  bf16x8 bfr[4][2];
  #pragma unroll
  for (int n=0;n<4;n++)
    #pragma unroll
    for (int kk=0;kk<2;kk++)
      bfr[n][kk] = *(const bf16x8*)(w3b + (n*16+col)*64 + kk*32 + kgrp*8);
  float bias[4];
  #pragma unroll
  for (int n=0;n<4;n++) bias[n] = b3[n*16+col];
  const f32x4* e04 = (const f32x4*)(sEg);
  const f32x4* e14 = (const f32x4*)(sEg + 64);
  const f32x4* e24 = (const f32x4*)(sEg + 128);
  __syncthreads();
  int p0 = (blockIdx.x*4 + wv)*64;
  int p = p0 + lane;
  float f0 = feats[3*p], f1 = feats[3*p+1], f2 = feats[3*p+2];
  int b = bidx[p];
  const f32x4* tb4 = (const f32x4*)&Tl[b*68];
  unsigned rowbase = (unsigned)(wv*64+lane)*32;
  unsigned sw = (lane&7)<<2;
  #pragma unroll
  for (int j=0;j<8;j++){
    unsigned w[4];
    #pragma unroll
    for (int h=0;h<2;h++){
      int cq = j*2 + h;
      f32x4 e0 = e04[cq], e1 = e14[cq], e2 = e24[cq], tp = tb4[cq];
      float y0 = fmaf(e0[0],f0, fmaf(e1[0],f1, fmaf(e2[0],f2, tp[0])));
      float y1 = fmaf(e0[1],f0, fmaf(e1[1],f1, fmaf(e2[1],f2, tp[1])));
      float y2 = fmaf(e0[2],f0, fmaf(e1[2],f1, fmaf(e2[2],f2, tp[2])));
      float y3 = fmaf(e0[3],f0, fmaf(e1[3],f1, fmaf(e2[3],f2, tp[3])));
      w[h*2]   = pack2bf(fmaxf(y0,0.f), fmaxf(y1,0.f));
      w[h*2+1] = pack2bf(fmaxf(y2,0.f), fmaxf(y3,0.f));
    }
    uint4 ch; ch.x=w[0]; ch.y=w[1]; ch.z=w[2]; ch.w=w[3];
    *(uint4*)&zbuf[rowbase + (((unsigned)(j*4)) ^ sw)] = ch;
  }
  asm volatile("s_waitcnt lgkmcnt(0)" ::: "memory");
  __builtin_amdgcn_sched_barrier(0);
  bf16x8 af[4][2];
  #pragma unroll
  for (int m=0;m<4;m++){
    int row = m*16 + col;
    unsigned rb = (unsigned)(wv*64+row)*32;
    unsigned sw2 = (unsigned)(row&7)<<2;
    #pragma unroll
    for (int kk=0;kk<2;kk++){
      unsigned off = ((unsigned)(kk*16 + kgrp*4)) ^ sw2;
      af[m][kk] = *(const bf16x8*)&zbuf[rb + off];
    }
  }
  asm volatile("s_waitcnt lgkmcnt(0)" ::: "memory");
  __builtin_amdgcn_sched_barrier(0);
  float* fwave = (float*)(SB + wv*8192);
  #pragma unroll
  for (int half=0; half<2; half++){
    f32x4 acc[2][4];
    #pragma unroll
    for (int mi=0;mi<2;mi++)
      #pragma unroll
      for (int n=0;n<4;n++)
        acc[mi][n] = (f32x4){0.f,0.f,0.f,0.f};
    #pragma unroll
    for (int kk=0;kk<2;kk++)
      #pragma unroll
      for (int mi=0;mi<2;mi++)
        #pragma unroll
        for (int n=0;n<4;n++)
          acc[mi][n] = __builtin_amdgcn_mfma_f32_16x16x32_bf16(af[half*2+mi][kk], bfr[n][kk], acc[mi][n], 0,0,0);
    #pragma unroll
    for (int mi=0;mi<2;mi++){
      #pragma unroll
      for (int n=0;n<4;n++){
        #pragma unroll
        for (int r=0;r<4;r++)
          fwave[(mi*16 + kgrp*4 + r)*64 + n*16 + col] = acc[mi][n][r] + bias[n];
      }
    }
    asm volatile("s_waitcnt lgkmcnt(0)" ::: "memory");
    __builtin_amdgcn_sched_barrier(0);
    #pragma unroll
    for (int it=0; it<8; it++){
      int idx = it*64 + lane;
      int r = idx >> 4;
      int c4 = (idx & 15) * 4;
      f32x4 v = *(const f32x4*)&fwave[r*64 + c4];
      int orow = p0 + half*32 + r;
      __builtin_nontemporal_store(v, (f32x4*)&out[(size_t)orow*64 + c4]);
    }
    asm volatile("s_waitcnt lgkmcnt(0)" ::: "memory");
    __builtin_amdgcn_sched_barrier(0);
  }
}

extern "C" void kernel_launch(void* const* d_in, const int* in_sizes, int n_in,
                              void* d_out, int out_size, void* d_ws, size_t ws_size,
                              hipStream_t stream) {
  const float* feats = (const float*)d_in[0];
  const int*   bidx  = (const int*)d_in[1];
  const float* W1 = (const float*)d_in[2];
  const float* g1 = (const float*)d_in[3];
  const float* b1 = (const float*)d_in[4];
  const float* W2 = (const float*)d_in[5];
  const float* g2 = (const float*)d_in[6];
  const float* b2 = (const float*)d_in[7];
  const float* W3 = (const float*)d_in[8];
  const float* b3 = (const float*)d_in[9];
  float* wsf = (float*)d_ws;
  float* out = (float*)d_out;
  kAC<<<512, 1024, 0, stream>>>(feats, bidx, W1, g1, wsf);
  kMx<<<128, 512, 0, stream>>>(W3, wsf);
  kB2<<<64, 128, 0, stream>>>(W1, g1, b1, W2, g2, b2, wsf);
  kF<<<1024, 256, 0, stream>>>(feats, bidx, wsf, b3, out);
}